// Round 14
// baseline (222.202 us; speedup 1.0000x reference)
//
#include <hip/hip_runtime.h>

// Q6ArithmeticLayer: out = softmax(-hs * 3*(1 - dot(normalize(tanh(x@W^T)), normalize(P))))
// x: (32768, 1024) fp32 -> 134 MB stream (roofline ~21 us @ 6.3-6.8 TB/s).
// R16 == R13 resubmit x3 (broker timeouts; R13/R14/R15 never executed).
// R13: cross-tail prefetch. R12 ((256,2), no spill, kernel ~60 us inferred from
//   dur~=kernel+135 fit) matches R2/R3's ~60 us despite different bodies: the
//   common factor is the serial tail (30 shfl + tanh/norm/softmax, ~1000+ cy)
//   during which a wave has ZERO loads outstanding, and lockstep wave starts
//   convoy the load phases -> HBM duty cycle ~50%. Fix: issue next iteration's
//   batch-A loads BEFORE the tail so 8 KB/wave stays in flight through it.
//   - loop: issue B -> compute A (hides B) -> issue next-A -> compute B ->
//     tail -> rotate. Peak live ~116 VGPR < 128 cap of (256,2) (no spill).
//   - conditional prefetch (wave-uniform) avoids wasted fetches on last iter.
//   - 512 blocks: 2048 waves x 4 tok x 4 iters = 32768; prefetch covers 3/4
//     iterations (vs 1/2 at 1024 blocks); 8 waves/CU x 8-16 KB in flight >>
//     ~22 KB/CU needed for 6.3 TB/s.
//   - body otherwise == refcheck-passing R8/R12: half-wave decomposition,
//     W in LDS (24 KB, SQ_LDS_BANK_CONFLICT=0), xor16 + xor{8,4,2,1} = 30 shfl.
// Predicted: kernel < 77 (invisible in top-5), dur 198 -> 165-180.
//   dur >= 193 falsifies tail-stall theory -> suspect harness floor next.

#define DIM 1024
#define NK 6
#define NPROTO 8
#define TPI 4  // tokens per wave iteration (2 per 32-lane half)

__global__ __launch_bounds__(256, 2) void q6_fused_kernel(
    const float* __restrict__ x,
    const float* __restrict__ W,
    const float* __restrict__ protos,
    const float* __restrict__ hs_ptr,
    float* __restrict__ out,
    int n_tokens, int n_waves)
{
    const int tid  = threadIdx.x;
    const int lane = tid & 63;
    const int wave_id = blockIdx.x * (blockDim.x >> 6) + (tid >> 6);
    const int h   = lane >> 5;    // which half: owns tokens {2h, 2h+1}
    const int sub = lane & 31;    // sub-lane within half (32 cols/token each)

    // --- stage W into LDS once per block: 6 x 1024 fp32 = 24 KB, straight copy ---
    __shared__ float4 wlds[NK * (DIM / 4)];   // wlds[k*256 + c] = W[k][4c..4c+3]
#pragma unroll
    for (int i = 0; i < (NK * DIM / 4) / 256; ++i)   // 6 iterations
        wlds[i * 256 + tid] = reinterpret_cast<const float4*>(W)[i * 256 + tid];

    // --- normalized prototype for this lane's proto slot (while W stage in flight) ---
    const int pl = lane & 7;
    float p[NK];
#pragma unroll
    for (int k = 0; k < NK; ++k) p[k] = protos[pl * NK + k];
    {
        float pn = sqrtf(p[0]*p[0] + p[1]*p[1] + p[2]*p[2] + p[3]*p[3] + p[4]*p[4] + p[5]*p[5]);
        float inv = 1.0f / fmaxf(pn, 1e-12f);
#pragma unroll
        for (int k = 0; k < NK; ++k) p[k] *= inv;
    }
    const float hs = hs_ptr[0];

    __syncthreads();

    const bool hi4 = (lane & 16) != 0;
    const int tloc = lane >> 4;   // 16-lane group g ends up owning token tb+g
    const int pidx = lane & 15;   // proto slot within the group (active if <8)
    const int step = n_waves * TPI;

    int tb = wave_id * TPI;
    if (tb >= n_tokens) return;

    // ---- preload batch A (j=0..3, cols 0..511) for the first iteration ----
    const float* xt0 = x + (size_t)(tb + 2 * h) * DIM + sub * 4;
    float4 xa[2][4];
#pragma unroll
    for (int j = 0; j < 4; ++j) {
        xa[0][j] = *reinterpret_cast<const float4*>(&xt0[j * 128]);
        xa[1][j] = *reinterpret_cast<const float4*>(&xt0[DIM + j * 128]);
    }

    for (; tb < n_tokens; ) {
        const float* xt = x + (size_t)(tb + 2 * h) * DIM + sub * 4;

        // ---- issue batch B loads (cols 512..1023); latency hides under compute A ----
        float4 xb[2][4];
#pragma unroll
        for (int j = 0; j < 4; ++j) {
            xb[0][j] = *reinterpret_cast<const float4*>(&xt[(j + 4) * 128]);
            xb[1][j] = *reinterpret_cast<const float4*>(&xt[DIM + (j + 4) * 128]);
        }

        float acc[2][NK];
#pragma unroll
        for (int t = 0; t < 2; ++t)
#pragma unroll
            for (int k = 0; k < NK; ++k) acc[t][k] = 0.0f;

        // ---- compute batch A ----
#pragma unroll
        for (int j = 0; j < 4; ++j) {
            float4 wk[NK];
#pragma unroll
            for (int k = 0; k < NK; ++k)
                wk[k] = wlds[k * 256 + j * 32 + sub];   // 2-way broadcast across halves
#pragma unroll
            for (int t = 0; t < 2; ++t) {
                const float4 xvj = xa[t][j];
#pragma unroll
                for (int k = 0; k < NK; ++k) {
                    float a = acc[t][k];
                    a = fmaf(xvj.x, wk[k].x, a);
                    a = fmaf(xvj.y, wk[k].y, a);
                    a = fmaf(xvj.z, wk[k].z, a);
                    a = fmaf(xvj.w, wk[k].w, a);
                    acc[t][k] = a;
                }
            }
        }

        // ---- PREFETCH next iteration's batch A: stays in flight through the tail ----
        const int tnext = tb + step;
        const bool has_next = (tnext < n_tokens);   // wave-uniform branch
        float4 xan[2][4];
        if (has_next) {
            const float* xtn = x + (size_t)(tnext + 2 * h) * DIM + sub * 4;
#pragma unroll
            for (int j = 0; j < 4; ++j) {
                xan[0][j] = *reinterpret_cast<const float4*>(&xtn[j * 128]);
                xan[1][j] = *reinterpret_cast<const float4*>(&xtn[DIM + j * 128]);
            }
        }

        // ---- compute batch B ----
#pragma unroll
        for (int j = 0; j < 4; ++j) {
            float4 wk[NK];
#pragma unroll
            for (int k = 0; k < NK; ++k)
                wk[k] = wlds[k * 256 + (j + 4) * 32 + sub];
#pragma unroll
            for (int t = 0; t < 2; ++t) {
                const float4 xvj = xb[t][j];
#pragma unroll
                for (int k = 0; k < NK; ++k) {
                    float a = acc[t][k];
                    a = fmaf(xvj.x, wk[k].x, a);
                    a = fmaf(xvj.y, wk[k].y, a);
                    a = fmaf(xvj.z, wk[k].z, a);
                    a = fmaf(xvj.w, wk[k].w, a);
                    acc[t][k] = a;
                }
            }
        }

        // ---- step 1: xor16 — token reduce-scatter within each half (6 shfl) ----
        float z[NK];
#pragma unroll
        for (int k = 0; k < NK; ++k) {
            float send = hi4 ? acc[0][k] : acc[1][k];
            float keep = hi4 ? acc[1][k] : acc[0][k];
            z[k] = keep + __shfl_xor(send, 16, 64);
        }

        // ---- steps 2-5: butterfly within the 16-lane group (24 shfl) ----
#pragma unroll
        for (int off = 8; off >= 1; off >>= 1)
#pragma unroll
            for (int k = 0; k < NK; ++k)
                z[k] += __shfl_xor(z[k], off, 64);

        // ---- epilogue: lanes p<8 of each group handle proto p of token tloc ----
        if (pidx < NPROTO) {
            float zz[NK];
            float nrm2 = 0.0f;
#pragma unroll
            for (int k = 0; k < NK; ++k) {
                float a = z[k];
                // tanh(a) = sign(a) * (1-e)/(1+e), e = exp(-2|a|) — hw v_exp_f32
                float e = __expf(-2.0f * fabsf(a));
                float th = (1.0f - e) / (1.0f + e);
                zz[k] = copysignf(th, a);
                nrm2 = fmaf(zz[k], zz[k], nrm2);
            }
            float inv = 1.0f / fmaxf(sqrtf(nrm2), 1e-6f);
            float dot = (zz[0]*p[0] + zz[1]*p[1] + zz[2]*p[2] +
                         zz[3]*p[3] + zz[4]*p[4] + zz[5]*p[5]) * inv;
            float logit = -hs * (6.0f - dot * 6.0f) * 0.5f;
            // softmax over the 8 proto lanes (xor 1,2,4 stays in the subgroup)
            float m = logit;
            m = fmaxf(m, __shfl_xor(m, 1, 64));
            m = fmaxf(m, __shfl_xor(m, 2, 64));
            m = fmaxf(m, __shfl_xor(m, 4, 64));
            float e = __expf(logit - m);
            float s = e;
            s += __shfl_xor(s, 1, 64);
            s += __shfl_xor(s, 2, 64);
            s += __shfl_xor(s, 4, 64);
            out[(size_t)(tb + tloc) * NPROTO + pidx] = e / s;
        }

        tb = tnext;
        if (has_next) {
#pragma unroll
            for (int t = 0; t < 2; ++t)
#pragma unroll
                for (int j = 0; j < 4; ++j) xa[t][j] = xan[t][j];
        }
    }
}

extern "C" void kernel_launch(void* const* d_in, const int* in_sizes, int n_in,
                              void* d_out, int out_size, void* d_ws, size_t ws_size,
                              hipStream_t stream) {
    const float* x      = (const float*)d_in[0];
    const float* W      = (const float*)d_in[1];
    const float* protos = (const float*)d_in[2];
    const float* hs     = (const float*)d_in[3];
    float* out = (float*)d_out;

    const int n_tokens = in_sizes[0] / DIM;   // 32768
    const int blocks = 512;                   // 2048 waves x 4 tok x 4 iters = 32768
    const int threads = 256;
    const int n_waves = blocks * (threads / 64);

    q6_fused_kernel<<<blocks, threads, 0, stream>>>(
        x, W, protos, hs, out, n_tokens, n_waves);
}

// Round 21
// 200.646 us; speedup vs baseline: 1.1074x; 1.1074x over previous
//
#include <hip/hip_runtime.h>

// Q6ArithmeticLayer: out = softmax(-hs * 3*(1 - dot(normalize(tanh(x@W^T)), normalize(P))))
// x: (32768, 1024) fp32 -> 134 MB stream (roofline ~21 us @ 6.3-6.8 TB/s).
// R23 == R18 resubmit x6 (broker/container failures; never executed).
// R18 = R17 + vmcnt FIFO fix on the last iteration: vmcnt(N) keeps the NEWEST
//   N entries; on the final iter the queue is [old store, cur 16 loads], so
//   vmcnt(1) kept the newest cur LOAD in flight (race on the last LDS chunk).
//   Now vmcnt(0) on the final iteration.
// R17: async global->LDS double-buffer (global_load_lds), zero-VGPR staging.
//   Evidence: every register-resident variant sits at 2.2-2.9 TB/s; R16's
//   32-reg prefetch spilled (VGPR=128, 43 MB scratch, 87-97 us > R12's ~60).
//   Waves spend ~85% of iteration time with 0 bytes in flight. Fix: keep
//   16 KB/wave ALWAYS in flight via DMA that costs no registers.
//   - 256 blocks x 4 waves, 1 block/CU. LDS = xlds[2][16][1024] (128K) + W (24K).
//   - each wave stages ITS OWN 4 tokens (16 x global_load_lds of 1 KB) and
//     computes only those -> NO barriers in the loop; per-wave counted vmcnt.
//   - steady-state vmcnt(17) verified by FIFO walk: queue at wait =
//     [cur 16, prior store, next 16]; drain to 17 removes exactly cur 16
//     (+stale store), leaving [store, next 16] in flight.
//   - compute = refcheck-proven R12 math; x from LDS (2-way aliasing free,
//     m136); W broadcast. __launch_bounds__(256,1): cap 256, live ~90.
// Predicted: VGPR 80-130, WRITE ~1 MB, FETCH ~137 MB, LDS 155648,
//   kernel 23-30 us, dur ~158-172. Occupancy ~12% is BY DESIGN.

#define DIM 1024
#define NK 6
#define NPROTO 8

__device__ __forceinline__ void gld_lds16(const float* g, float* l) {
    // global src is per-lane (lane i's address in g's VGPR pair); LDS dst is
    // wave-uniform base, HW writes base + lane*16.
    __builtin_amdgcn_global_load_lds(
        (const __attribute__((address_space(1))) void*)g,
        (__attribute__((address_space(3))) void*)l,
        16, 0, 0);
}

__global__ __launch_bounds__(256, 1) void q6_fused_kernel(
    const float* __restrict__ x,
    const float* __restrict__ W,
    const float* __restrict__ protos,
    const float* __restrict__ hs_ptr,
    float* __restrict__ out,
    int n_tokens, int n_iters)
{
    __shared__ float  xlds[2][16][DIM];     // 128 KB: 2 buffers x 16 tokens
    __shared__ float4 wlds[NK * (DIM / 4)]; // 24 KB

    const int tid  = threadIdx.x;
    const int lane = tid & 63;
    const int w    = tid >> 6;     // wave in block; owns tokens w*4..w*4+3
    const int h    = lane >> 5;    // half: token pair {2h, 2h+1} of the wave's 4
    const int sub  = lane & 31;

    // --- stage W into LDS (cooperative, once) ---
#pragma unroll
    for (int i = 0; i < (NK * DIM / 4) / 256; ++i)
        wlds[i * 256 + tid] = reinterpret_cast<const float4*>(W)[i * 256 + tid];

    // --- normalized prototype for this lane's proto slot ---
    const int pl = lane & 7;
    float p[NK];
#pragma unroll
    for (int k = 0; k < NK; ++k) p[k] = protos[pl * NK + k];
    {
        float pn = sqrtf(p[0]*p[0] + p[1]*p[1] + p[2]*p[2] + p[3]*p[3] + p[4]*p[4] + p[5]*p[5]);
        float inv = 1.0f / fmaxf(pn, 1e-12f);
#pragma unroll
        for (int k = 0; k < NK; ++k) p[k] *= inv;
    }
    const float hs = hs_ptr[0];

    __syncthreads();   // wlds visible to all waves; drains all prologue mem ops

    const bool hi4 = (lane & 16) != 0;
    const int tloc = lane >> 4;   // group g owns token (wave base + g)
    const int pidx = lane & 15;

    // ---- stage iteration 0 into buffer 0 (16 x 1KB async) ----
    {
        const int gb0 = blockIdx.x * n_iters * 16;
        const float* sb = x + (size_t)(gb0 + w * 4) * DIM + lane * 4;
        float* db = &xlds[0][w * 4][0];
#pragma unroll
        for (int tt = 0; tt < 4; ++tt)
#pragma unroll
            for (int c = 0; c < 4; ++c)
                gld_lds16(sb + tt * DIM + c * 256, db + tt * DIM + c * 256);
    }

    for (int it = 0; it < n_iters; ++it) {
        const int cur = it & 1;
        const int gb  = (blockIdx.x * n_iters + it) * 16;
        const bool has_next = (it + 1 < n_iters);

        // ---- stage next iteration into the other buffer (async, no wait) ----
        if (has_next) {
            const float* sb = x + (size_t)(gb + 16 + w * 4) * DIM + lane * 4;
            float* db = &xlds[cur ^ 1][w * 4][0];
#pragma unroll
            for (int tt = 0; tt < 4; ++tt)
#pragma unroll
                for (int c = 0; c < 4; ++c)
                    gld_lds16(sb + tt * DIM + c * 256, db + tt * DIM + c * 256);
        }

        // ---- wait for CURRENT buffer only (FIFO: drain oldest, keep newest) ----
        if (has_next) {
            if (it == 0) asm volatile("s_waitcnt vmcnt(16)" ::: "memory");
            else         asm volatile("s_waitcnt vmcnt(17)" ::: "memory");
        } else {
            // final iteration: cur loads are the NEWEST entries -> full drain
            asm volatile("s_waitcnt vmcnt(0)" ::: "memory");
        }

        // ---- compute this wave's 4 tokens from LDS (R12 math unchanged) ----
        const float* xr0 = &xlds[cur][w * 4 + 2 * h][sub * 4];
        const float* xr1 = xr0 + DIM;

        float acc[2][NK];
#pragma unroll
        for (int t = 0; t < 2; ++t)
#pragma unroll
            for (int k = 0; k < NK; ++k) acc[t][k] = 0.0f;

#pragma unroll
        for (int j = 0; j < 8; ++j) {
            float4 wk[NK];
#pragma unroll
            for (int k = 0; k < NK; ++k)
                wk[k] = wlds[k * 256 + j * 32 + sub];   // broadcast across halves
            const float4 xA = *reinterpret_cast<const float4*>(&xr0[j * 128]);
            const float4 xB = *reinterpret_cast<const float4*>(&xr1[j * 128]);
#pragma unroll
            for (int k = 0; k < NK; ++k) {
                float a0 = acc[0][k];
                a0 = fmaf(xA.x, wk[k].x, a0);
                a0 = fmaf(xA.y, wk[k].y, a0);
                a0 = fmaf(xA.z, wk[k].z, a0);
                a0 = fmaf(xA.w, wk[k].w, a0);
                acc[0][k] = a0;
                float a1 = acc[1][k];
                a1 = fmaf(xB.x, wk[k].x, a1);
                a1 = fmaf(xB.y, wk[k].y, a1);
                a1 = fmaf(xB.z, wk[k].z, a1);
                a1 = fmaf(xB.w, wk[k].w, a1);
                acc[1][k] = a1;
            }
        }

        // ---- xor16 token reduce-scatter (6 shfl): group g owns token base+g ----
        float z[NK];
#pragma unroll
        for (int k = 0; k < NK; ++k) {
            float send = hi4 ? acc[0][k] : acc[1][k];
            float keep = hi4 ? acc[1][k] : acc[0][k];
            z[k] = keep + __shfl_xor(send, 16, 64);
        }

        // ---- butterfly within the 16-lane group (24 shfl) ----
#pragma unroll
        for (int off = 8; off >= 1; off >>= 1)
#pragma unroll
            for (int k = 0; k < NK; ++k)
                z[k] += __shfl_xor(z[k], off, 64);

        // ---- epilogue: lanes p<8 of each group -> proto p of token tloc ----
        if (pidx < NPROTO) {
            float zz[NK];
            float nrm2 = 0.0f;
#pragma unroll
            for (int k = 0; k < NK; ++k) {
                float a = z[k];
                float e = __expf(-2.0f * fabsf(a));
                float th = (1.0f - e) / (1.0f + e);
                zz[k] = copysignf(th, a);
                nrm2 = fmaf(zz[k], zz[k], nrm2);
            }
            float inv = 1.0f / fmaxf(sqrtf(nrm2), 1e-6f);
            float dot = (zz[0]*p[0] + zz[1]*p[1] + zz[2]*p[2] +
                         zz[3]*p[3] + zz[4]*p[4] + zz[5]*p[5]) * inv;
            float logit = -hs * (6.0f - dot * 6.0f) * 0.5f;
            float m = logit;
            m = fmaxf(m, __shfl_xor(m, 1, 64));
            m = fmaxf(m, __shfl_xor(m, 2, 64));
            m = fmaxf(m, __shfl_xor(m, 4, 64));
            float e = __expf(logit - m);
            float s = e;
            s += __shfl_xor(s, 1, 64);
            s += __shfl_xor(s, 2, 64);
            s += __shfl_xor(s, 4, 64);
            out[(size_t)(gb + w * 4 + tloc) * NPROTO + pidx] = e / s;
        }
    }
}

extern "C" void kernel_launch(void* const* d_in, const int* in_sizes, int n_in,
                              void* d_out, int out_size, void* d_ws, size_t ws_size,
                              hipStream_t stream) {
    const float* x      = (const float*)d_in[0];
    const float* W      = (const float*)d_in[1];
    const float* protos = (const float*)d_in[2];
    const float* hs     = (const float*)d_in[3];
    float* out = (float*)d_out;

    const int n_tokens = in_sizes[0] / DIM;   // 32768
    const int blocks  = 256;                  // 1 block/CU (152 KB LDS)
    const int threads = 256;                  // 4 waves x 4 tokens = 16 tok/block-iter
    const int n_iters = n_tokens / (blocks * 16);  // 8

    q6_fused_kernel<<<blocks, threads, 0, stream>>>(
        x, W, protos, hs, out, n_tokens, n_iters);
}